// Round 15
// baseline (121.269 us; speedup 1.0000x reference)
//
#include <hip/hip_runtime.h>
#include <cmath>

// CapsuleLayer routing, B=64, Ni=2048, Di=16, No=32, Do=16 (fp32 in/out).
// R19 = R17 fused kernel (best passing: 114.79us, byte-identical) + the
// R10-form regridded reduce, ISOLATED this time: 2048 blocks x 256 thr,
// one (b,o) pair per block, 16 strided loads/thread, 8 blocks/CU = 32
// waves/CU (was 512 blocks = 2 blocks/CU = 8 waves/CU). The reduce is a
// pure latency-bound strided gather (64KB-apart loads); 4x resident waves
// = 4x outstanding loads. R10 bundled this with 2 other changes (net null);
// mechanism is sound, now isolated.
// R18 post-mortem: 2-n-per-iter amortization failed correctness (absmax
// 0.877, bug not identifiable by inspection) -> line abandoned per rigor.
// Fused kernel keeps (all verified): bf16-only W (one MFMA/oo), hS4
// q-partial rowsums, fp16 partials, DPP row_ror routing, 2-way b-split,
// XOR-swizzled pad-free LDS (conflicts 0), cvt_pk staging, 2-barrier
// single-buffer pipeline with prefetch 2 ahead, (512,4) bounds, XCD
// pairing, gidx-major epilogue.

#define NI 2048
#define NGROUPS 256
#define NPER 8

typedef short bf16x8 __attribute__((ext_vector_type(8)));
typedef float f32x4 __attribute__((ext_vector_type(4)));

static __device__ __forceinline__ unsigned cvt_pk_bf16(float a, float b) {
  unsigned r;
  asm("v_cvt_pk_bf16_f32 %0, %1, %2" : "=v"(r) : "v"(a), "v"(b));
  return r;  // lo16 = bf16(a), hi16 = bf16(b), RNE
}
// fp32 -> (hi bf16x4, lo bf16x4) with hi+lo ~ full precision (x staging)
static __device__ __forceinline__ void split4_pk(float4 v, uint2& hi, uint2& lo) {
  hi.x = cvt_pk_bf16(v.x, v.y);
  hi.y = cvt_pk_bf16(v.z, v.w);
  float r0 = v.x - __uint_as_float(hi.x << 16);
  float r1 = v.y - __uint_as_float(hi.x & 0xFFFF0000u);
  float r2 = v.z - __uint_as_float(hi.y << 16);
  float r3 = v.w - __uint_as_float(hi.y & 0xFFFF0000u);
  lo.x = cvt_pk_bf16(r0, r1);
  lo.y = cvt_pk_bf16(r2, r3);
}
// fp32x4 -> bf16x4 (hi only, W staging — R17-proven)
static __device__ __forceinline__ uint2 pack4_bf16(float4 v) {
  uint2 hi;
  hi.x = cvt_pk_bf16(v.x, v.y);
  hi.y = cvt_pk_bf16(v.z, v.w);
  return hi;
}
// dword offset of 16B unit u (0/1) of row r in a rows-of-8-dwords array,
// XOR-swizzled so stride-8 row reads spread across banks (both sides use it).
static __device__ __forceinline__ int swz8(int r, int u) {
  return r * 8 + ((u ^ ((r >> 2) & 1)) << 2);
}
// fp32 <-> fp16 scalar converts
static __device__ __forceinline__ unsigned short f2h(float f) {
  _Float16 h = (_Float16)f;
  union { _Float16 h; unsigned short u; } c; c.h = h; return c.u;
}
static __device__ __forceinline__ float h2f(unsigned short u) {
  union { _Float16 h; unsigned short u; } c; c.u = u; return (float)c.h;
}
// DPP rotate within 16-lane rows: ctrl 0x120|N = row_ror:N (R13/R15-proven)
template<int CTRL>
static __device__ __forceinline__ float dpp_rot(float v) {
  return __int_as_float(__builtin_amdgcn_mov_dpp(__float_as_int(v), CTRL, 0xF, 0xF, true));
}
static __device__ __forceinline__ float sum16_dpp(float v) {
  v += dpp_rot<0x128>(v); v += dpp_rot<0x124>(v);
  v += dpp_rot<0x122>(v); v += dpp_rot<0x121>(v);
  return v;
}
static __device__ __forceinline__ float max16_dpp(float v) {
  v = fmaxf(v, dpp_rot<0x128>(v)); v = fmaxf(v, dpp_rot<0x124>(v));
  v = fmaxf(v, dpp_rot<0x122>(v)); v = fmaxf(v, dpp_rot<0x121>(v));
  return v;
}

// ---------------- Fused kernel: MFMA + in-block routing + weighted accumulate ----
// grid 512; xcd = bx&7, slot = bx>>3 (0..63); ng = xcd*32 + (slot>>1); bh = slot&1
// block 512 = 8 waves = (bt = wv&1: 16-b tile) x (oq = wv>>1: o-octet).
// A = [Whi|Whi] (m=d, K=32 dup), B = [x_hi; x_lo] stacked along K.
// LDS dword offsets:
#define WAOFF 0        // 32 o * 16 rows (d) * 8 = 4096 (swizzled, bf16 hi only)
#define XBOFF 4096     // 64 rows (s*32 + b_local) * 8 = 512 (swizzled)
#define H4OFF 4608     // hS4[b][o][q]: 32 rows * 132 (32*4 + 4 pad) = 4224
#define C2OFF 8832     // c2[o][b_local]: 32 * 33 = 1056
#define LDSZ  9888     // 39.6 KB -> 2 blocks/CU
__global__ __launch_bounds__(512, 4) void caps_fused_kernel(
    const float* __restrict__ x, const float* __restrict__ W,
    unsigned short* __restrict__ partial)
{
  const int bx = blockIdx.x;
  const int xcd = bx & 7, slot = bx >> 3;
  const int ng = xcd * 32 + (slot >> 1);
  const int bh = slot & 1;
  const int t = threadIdx.x;
  const int wv = t >> 6, l = t & 63;
  const int q = l >> 4, dq = l & 15, qh = q & 1, sx = q >> 1;
  const int bt = wv & 1, oq = wv >> 1;

  __shared__ __align__(16) float lds[LDSZ];
  float* WA  = lds + WAOFF;
  float* XB  = lds + XBOFF;
  float* hS4 = lds + H4OFF;
  float* c2S = lds + C2OFF;

  float sacc[8][4];
  #pragma unroll
  for (int oo = 0; oo < 8; ++oo)
    { sacc[oo][0] = 0.f; sacc[oo][1] = 0.f; sacc[oo][2] = 0.f; sacc[oo][3] = 0.f; }

  const int n0 = ng * NPER;
  // staging decompositions: W chunk c covers o = c*8 + wv; (d, i4) from t
  const int wd = (t >> 2) & 15, wi4 = t & 3;
  const int wu = wi4 >> 1, wsub = (wi4 & 1) * 2;
  const int xb = t >> 2, xi4 = t & 3;          // x staging: t < 128 (32 b)
  const int xu = xi4 >> 1, xsub = (xi4 & 1) * 2;
  // hS4 write base for this lane: row b = bt*16+dq, column block q
  const int h4w = (bt * 16 + dq) * 132 + q;

  // ---- prologue: load + stage n0, then prefetch n0+1 ----
  float4 wreg[4];
  float4 xreg = make_float4(0.f, 0.f, 0.f, 0.f);
  #pragma unroll
  for (int c = 0; c < 4; ++c)
    wreg[c] = *(const float4*)(W + (size_t)n0 * 8192 + c * 2048 + 4 * t);
  if (t < 128)
    xreg = *(const float4*)(x + (size_t)(bh * 32 + xb) * (NI * 16) + n0 * 16 + xi4 * 4);

  #pragma unroll
  for (int c = 0; c < 4; ++c)
    *(uint2*)&WA[swz8((c * 8 + wv) * 16 + wd, wu) + wsub] = pack4_bf16(wreg[c]);
  if (t < 128) {
    uint2 hi, lo;
    split4_pk(xreg, hi, lo);
    *(uint2*)&XB[swz8(xb, xu) + xsub] = hi;
    *(uint2*)&XB[swz8(32 + xb, xu) + xsub] = lo;
  }
  __syncthreads();

  {
    const size_t nb = (size_t)(n0 + 1);
    #pragma unroll
    for (int c = 0; c < 4; ++c)
      wreg[c] = *(const float4*)(W + nb * 8192 + c * 2048 + 4 * t);
    if (t < 128)
      xreg = *(const float4*)(x + (size_t)(bh * 32 + xb) * (NI * 16) + nb * 16 + xi4 * 4);
  }

  #pragma unroll 1
  for (int nn = 0; nn < NPER; ++nn) {
    // ---- phase 1: one MFMA per oo; q-partial rowsums -> hS4 ----
    f32x4 Dv[8];
    {
      // B frag: K-slice q*8..+7 -> rows (q>>1)*32 + b (x_hi for q<2, x_lo else)
      bf16x8 B = *(const bf16x8*)&XB[swz8(sx * 32 + bt * 16 + dq, qh)];
      #pragma unroll
      for (int oo = 0; oo < 8; ++oo) {
        const int o = oq * 8 + oo;
        // A frag: Whi row (o*16+d), i-slice qh*8 (dup along K for q>=2)
        bf16x8 A = *(const bf16x8*)&WA[swz8(o * 16 + dq, qh)];
        f32x4 D = {0.f, 0.f, 0.f, 0.f};
        D = __builtin_amdgcn_mfma_f32_16x16x32_bf16(A, B, D, 0, 0, 0);
        Dv[oo] = D;
        hS4[h4w + o * 4] = D[0] + D[1] + D[2] + D[3];  // q-partial of h[b][o]
      }
    }
    __syncthreads();   // syncA: hS4 ready; MFMA reads of WA/XB(nn) complete

    // ---- phase 2a: stage data nn+1 into WA/XB (pipelined, single buffer) ----
    if (nn < NPER - 1) {
      #pragma unroll
      for (int c = 0; c < 4; ++c)
        *(uint2*)&WA[swz8((c * 8 + wv) * 16 + wd, wu) + wsub] = pack4_bf16(wreg[c]);
      if (t < 128) {
        uint2 hi, lo;
        split4_pk(xreg, hi, lo);
        *(uint2*)&XB[swz8(xb, xu) + xsub] = hi;
        *(uint2*)&XB[swz8(32 + xb, xu) + xsub] = lo;
      }
    }

    // ---- phase 2b: routing; h = sum of 4 q-partials (b128 reads);
    //      16-lane reduces via DPP row_ror (R15-proven) ----
    {
      const int bl = t >> 4, op = t & 15;
      f32x4 ha = *(const f32x4*)&hS4[bl * 132 + op * 4];
      f32x4 hb = *(const f32x4*)&hS4[bl * 132 + (op + 16) * 4];
      const float h0 = (ha[0] + ha[1]) + (ha[2] + ha[3]);
      const float h1 = (hb[0] + hb[1]) + (hb[2] + hb[3]);
      const float b10 = h0 * 0.03125f, b11 = h1 * 0.03125f;
      const float mx = max16_dpp(fmaxf(b10, b11));
      const float e0 = __expf(b10 - mx), e1 = __expf(b11 - mx);
      const float S = sum16_dpp(e0 + e1);
      const float inv = 1.0f / S;
      const float b20 = b10 + e0 * inv * h0, b21 = b11 + e1 * inv * h1;
      const float mx2 = max16_dpp(fmaxf(b20, b21));
      const float e20 = __expf(b20 - mx2), e21 = __expf(b21 - mx2);
      const float S2 = sum16_dpp(e20 + e21);
      const float inv2 = 1.0f / S2;
      c2S[op * 33 + bl] = e20 * inv2;
      c2S[(op + 16) * 33 + bl] = e21 * inv2;
    }

    // ---- phase 2c: issue global prefetch for nn+2 ----
    if (nn < NPER - 2) {
      const size_t nb = (size_t)(n0 + nn + 2);
      #pragma unroll
      for (int c = 0; c < 4; ++c)
        wreg[c] = *(const float4*)(W + nb * 8192 + c * 2048 + 4 * t);
      if (t < 128)
        xreg = *(const float4*)(x + (size_t)(bh * 32 + xb) * (NI * 16) + nb * 16 + xi4 * 4);
    }
    __syncthreads();   // syncB: c2S ready; WA/XB(nn+1) staged

    // ---- phase 3: weighted accumulate from retained D ----
    #pragma unroll
    for (int oo = 0; oo < 8; ++oo) {
      const int o = oq * 8 + oo;
      const float c = c2S[o * 33 + bt * 16 + dq];
      sacc[oo][0] += c * Dv[oo][0]; sacc[oo][1] += c * Dv[oo][1];
      sacc[oo][2] += c * Dv[oo][2]; sacc[oo][3] += c * Dv[oo][3];
    }
    // c2S reads here precede the next syncA; next c2S writes come after it.
    // hS4(nn+1) writes come after syncB -> don't race phase-2b reads of (nn).
  }

  // ---- epilogue: gidx-major, block-contiguous, fp16 partials ----
  // partial[ng][b_global][cell], cell = o*16 + d (half elements), d = q*4 + r
  unsigned short* pb = partial + (size_t)ng * 32768
            + (size_t)(bh * 32 + bt * 16 + dq) * 512 + q * 4;
  #pragma unroll
  for (int oo = 0; oo < 8; ++oo) {
    const int o = oq * 8 + oo;
    ushort4 v;
    v.x = f2h(sacc[oo][0]); v.y = f2h(sacc[oo][1]);
    v.z = f2h(sacc[oo][2]); v.w = f2h(sacc[oo][3]);
    *(ushort4*)(pb + o * 16) = v;
  }
}

// ---------------- Kernel 2: reduce 256 fp16 group-partials + squash ----------------
// R19 regrid (isolated): one (b,o) pair per block, 2048 blocks x 256 thr =
// 16 group-chunks x 16 d; 16 strided loads/thread; 8 blocks/CU = 32 waves/CU.
__global__ __launch_bounds__(256) void caps_reduce_kernel(
    const unsigned short* __restrict__ partial, float* __restrict__ out)
{
  const int t = threadIdx.x;
  const int pair = blockIdx.x;              // (b,o), 2048 total
  const int b = pair >> 5, o = pair & 31;
  const int d = t & 15, g16 = t >> 4;
  const unsigned short* p = partial + (size_t)b * 512 + o * 16 + d;
  float s = 0.f;
  #pragma unroll
  for (int k = 0; k < 16; ++k)
    s += h2f(p[(size_t)(g16 + k * 16) * 32768]);
  __shared__ float red[16][17];
  red[g16][d] = s;
  __syncthreads();
  if (t < 16) {
    float sd = 0.f;
    #pragma unroll
    for (int g = 0; g < 16; ++g) sd += red[g][t];
    float s2 = sd * sd;
    s2 += __shfl_xor(s2, 1); s2 += __shfl_xor(s2, 2);
    s2 += __shfl_xor(s2, 4); s2 += __shfl_xor(s2, 8);   // over d (lanes 0-15)
    float scale = s2 / (1.0f + s2) / sqrtf(s2 + 1e-7f);
    out[(size_t)b * 512 + o * 16 + t] = scale * sd;
  }
}

extern "C" void kernel_launch(void* const* d_in, const int* in_sizes, int n_in,
                              void* d_out, int out_size, void* d_ws, size_t ws_size,
                              hipStream_t stream) {
  const float* x = (const float*)d_in[0];   // [64,2048,16]
  const float* W = (const float*)d_in[1];   // [1,2048,32,16,16]
  if (in_sizes[0] != 64 * 2048 * 16) { const float* tmp = x; x = W; W = tmp; }
  float* out = (float*)d_out;               // [64,32,16]

  unsigned short* partial = (unsigned short*)d_ws;  // 256*32768 fp16 = 16.8 MB

  caps_fused_kernel<<<512, 512, 0, stream>>>(x, W, partial);
  caps_reduce_kernel<<<2048, 256, 0, stream>>>(partial, out);
}